// Round 3
// baseline (23.137 us; speedup 1.0000x reference)
//
#include <hip/hip_runtime.h>
#include <math.h>

#define DIM 512
#define BATCH 1024
#define NPAIR (DIM * (DIM - 1) / 2)

// ws layout (floats): M[512*512] at 0 ; partial[NCHUNK][BATCH] after it
#define PART_OFF (DIM * DIM)

// Wp element (i,j), j>i, lives at Wp[i*(DIM-2) - i(i-1)/2 - 1 + j]

// ---------- kernel 1: build dense symmetric M, fully coalesced via tile transpose ----
#define NT 16   // 16x16 grid of 32x32 tiles; upper tile pairs only
__global__ __launch_bounds__(256)
void build_M(const float* __restrict__ W, float* __restrict__ M) {
    // map bid -> (ti, tj) with ti <= tj
    int bid = blockIdx.x;
    int ti = 0, base = 0;
    while (base + (NT - ti) <= bid) { base += NT - ti; ++ti; }
    const int tj = ti + (bid - base);
    const int tx  = threadIdx.x & 31;
    const int ty8 = threadIdx.x >> 5;          // 0..7
    const int i0 = ti * 32, j0 = tj * 32;
    const float* Wp  = W + DIM;
    const float* Wsq = W + DIM + NPAIR;

    __shared__ float ld[32][33];

    #pragma unroll
    for (int s = 0; s < 4; ++s) {
        const int iy = ty8 + s * 8;
        const int i = i0 + iy, j = j0 + tx;
        float v = 0.f;
        if (j > i)       v = 0.5f * Wp[i * (DIM - 2) - (i * (i - 1)) / 2 - 1 + j];
        else if (j == i) v = Wsq[i];
        ld[iy][tx] = v;
        if (j >= i) M[(size_t)i * DIM + j] = v;   // coalesced row write
    }
    __syncthreads();
    #pragma unroll
    for (int s = 0; s < 4; ++s) {
        const int a = ty8 + s * 8;                 // col within loaded tile
        const int jj = j0 + a, ii = i0 + tx;
        if (jj > ii) M[(size_t)jj * DIM + ii] = ld[tx][a];  // coalesced, LDS stride-33
    }
}

// ---------- kernel 2: fused t = M x (per i-chunk) + partial dot ----------
#define TPB2 1024
#define ROWS 16
#define NCHUNK 4
#define CHUNK (DIM / NCHUNK)   // 128

__global__ __launch_bounds__(TPB2, 4)
void gemv_quad(const float* __restrict__ x, const float* __restrict__ W,
               const float* __restrict__ M, float* __restrict__ partial) {
    const int rg  = blockIdx.x >> 2;    // row-group 0..63
    const int c   = blockIdx.x & 3;     // i-chunk 0..3
    const int tid = threadIdx.x;
    const int jt  = tid & 127;          // j-quad owner (128 quads = 512 cols)
    const int g   = tid >> 7;           // i-subgroup 0..7 (wave-uniform)
    const int row0 = rg * ROWS;
    const int i0   = c * CHUNK;
    const int j4   = jt * 4;

    __shared__ float xs[CHUNK][20];     // stride 20: 16B-aligned rows, 8-way-max write conflict
    __shared__ float red[TPB2 / 64][ROWS];

    // stage x[row0..row0+15][i0..i0+127]: 2048 elems, 2 per thread, coalesced
    #pragma unroll
    for (int k = 0; k < 2; ++k) {
        const int p = tid + k * TPB2;
        const int ii = p & 127, r = p >> 7;
        xs[ii][r] = x[(size_t)(row0 + r) * DIM + i0 + ii];
    }
    __syncthreads();

    // acc[r] = t_j quad for row r; fold W_lin into exactly one (c,g) slice
    float4 acc[ROWS];
    if (c == 0 && g == 0) {
        const float4 wl = *(const float4*)(W + j4);
        #pragma unroll
        for (int r = 0; r < ROWS; ++r) acc[r] = wl;
    } else {
        #pragma unroll
        for (int r = 0; r < ROWS; ++r) acc[r] = make_float4(0.f, 0.f, 0.f, 0.f);
    }

    const float* mp = M + (size_t)(i0 + g * 16) * DIM + j4;

    #pragma unroll 2
    for (int it = 0; it < 16; ++it) {
        const float4 w = *(const float4*)mp;            // coalesced 16B/lane, L2-hit
        const float* xp = &xs[g * 16 + it][0];
        const float4 xa = *(const float4*)(xp + 0);     // broadcast reads (uniform addr)
        const float4 xb = *(const float4*)(xp + 4);
        const float4 xc = *(const float4*)(xp + 8);
        const float4 xd = *(const float4*)(xp + 12);
        #define FMA4(A, S) A.x = fmaf(S, w.x, A.x); A.y = fmaf(S, w.y, A.y); \
                           A.z = fmaf(S, w.z, A.z); A.w = fmaf(S, w.w, A.w)
        FMA4(acc[0],  xa.x); FMA4(acc[1],  xa.y); FMA4(acc[2],  xa.z); FMA4(acc[3],  xa.w);
        FMA4(acc[4],  xb.x); FMA4(acc[5],  xb.y); FMA4(acc[6],  xb.z); FMA4(acc[7],  xb.w);
        FMA4(acc[8],  xc.x); FMA4(acc[9],  xc.y); FMA4(acc[10], xc.z); FMA4(acc[11], xc.w);
        FMA4(acc[12], xd.x); FMA4(acc[13], xd.y); FMA4(acc[14], xd.z); FMA4(acc[15], xd.w);
        #undef FMA4
        mp += DIM;
    }

    // y[r] = sum over this thread's j-quad of x[row][j] * t[row][j]
    float y[ROWS];
    #pragma unroll
    for (int r = 0; r < ROWS; ++r) {
        const float4 xq = *(const float4*)&x[(size_t)(row0 + r) * DIM + j4];
        y[r] = xq.x * acc[r].x + xq.y * acc[r].y + xq.z * acc[r].z + xq.w * acc[r].w;
    }

    // 64-lane butterfly
    #pragma unroll
    for (int off = 32; off > 0; off >>= 1) {
        #pragma unroll
        for (int r = 0; r < ROWS; ++r) y[r] += __shfl_xor(y[r], off);
    }

    const int wave = tid >> 6, lane = tid & 63;
    if (lane == 0) {
        #pragma unroll
        for (int r = 0; r < ROWS; ++r) red[wave][r] = y[r];
    }
    __syncthreads();
    if (tid < ROWS) {
        float z = 0.f;
        #pragma unroll
        for (int w = 0; w < TPB2 / 64; ++w) z += red[w][tid];
        partial[c * BATCH + row0 + tid] = z;   // deterministic, no atomics
    }
}

// ---------- kernel 3: sum chunk partials + bias, sigmoid ----------
__global__ void finalize(const float* __restrict__ partial, const float* __restrict__ bias,
                         float* __restrict__ out) {
    const int b = blockIdx.x * 256 + threadIdx.x;
    float z = partial[b] + partial[BATCH + b] + partial[2 * BATCH + b] +
              partial[3 * BATCH + b] + bias[0];
    out[b] = 1.0f / (1.0f + expf(-z));
}

extern "C" void kernel_launch(void* const* d_in, const int* in_sizes, int n_in,
                              void* d_out, int out_size, void* d_ws, size_t ws_size,
                              hipStream_t stream) {
    const float* x = (const float*)d_in[0];   // [1024, 512]
    const float* W = (const float*)d_in[1];   // [1, 131840]
    const float* b = (const float*)d_in[2];   // [1]
    float* out = (float*)d_out;               // [1024]

    float* M       = (float*)d_ws;            // 1 MB
    float* partial = (float*)d_ws + PART_OFF; // 16 KB

    const int ntiles = NT * (NT + 1) / 2;     // 136
    hipLaunchKernelGGL(build_M,   dim3(ntiles),          dim3(256),  0, stream, W, M);
    hipLaunchKernelGGL(gemv_quad, dim3(64 * NCHUNK),     dim3(TPB2), 0, stream, x, W, M, partial);
    hipLaunchKernelGGL(finalize,  dim3(BATCH / 256),     dim3(256),  0, stream, partial, b, out);
}

// Round 4
// 17.388 us; speedup vs baseline: 1.3306x; 1.3306x over previous
//
#include <hip/hip_runtime.h>
#include <math.h>

#define DIM 512
#define BATCH 1024
#define NPAIR (DIM * (DIM - 1) / 2)

typedef short bf16x8 __attribute__((ext_vector_type(8)));
typedef float f32x4  __attribute__((ext_vector_type(4)));

// ---- bf16 split helpers (RTN-even) ----
__device__ __forceinline__ unsigned short f2bf(float f) {
    unsigned int u = __float_as_uint(f);
    u += 0x7fff + ((u >> 16) & 1);
    return (unsigned short)(u >> 16);
}
__device__ __forceinline__ float bf2f(unsigned short h) {
    return __uint_as_float(((unsigned int)h) << 16);
}

// ws layout (ushort elems): Mh @0 [512*512], Ml @262144, Xh @524288 [1024*512], Xl @1048576
// partial (float) @ byte 3145728: [16][1024]
#define MH_OFF 0
#define ML_OFF (DIM * DIM)
#define XH_OFF (2 * DIM * DIM)
#define XL_OFF (2 * DIM * DIM + BATCH * DIM)
#define PART_BYTE_OFF (2 * (size_t)(2 * DIM * DIM + 2 * BATCH * DIM))

// ---------------- kernel 1: prep (M triangle->dense hi/lo + X hi/lo) ----------------
#define NT 16
__global__ __launch_bounds__(256)
void prep(const float* __restrict__ x, const float* __restrict__ W,
          unsigned short* __restrict__ Mh, unsigned short* __restrict__ Ml,
          unsigned short* __restrict__ Xh, unsigned short* __restrict__ Xl) {
    const int bid = blockIdx.x;
    if (bid < 136) {
        // map bid -> (ti, tj), ti <= tj
        int ti = 0, base = 0;
        while (base + (NT - ti) <= bid) { base += NT - ti; ++ti; }
        const int tj = ti + (bid - base);
        const int tx = threadIdx.x & 31, ty8 = threadIdx.x >> 5;
        const int i0 = ti * 32, j0 = tj * 32;
        const float* Wp  = W + DIM;
        const float* Wsq = W + DIM + NPAIR;
        __shared__ float ld[32][33];
        #pragma unroll
        for (int s = 0; s < 4; ++s) {
            const int iy = ty8 + s * 8;
            const int i = i0 + iy, j = j0 + tx;
            float v = 0.f;
            if (j > i)       v = 0.5f * Wp[i * (DIM - 2) - (i * (i - 1)) / 2 - 1 + j];
            else if (j == i) v = Wsq[i];
            ld[iy][tx] = v;
            if (j >= i) {
                unsigned short h = f2bf(v);
                Mh[i * DIM + j] = h;
                Ml[i * DIM + j] = f2bf(v - bf2f(h));
            }
        }
        __syncthreads();
        #pragma unroll
        for (int s = 0; s < 4; ++s) {
            const int a = ty8 + s * 8;
            const int jj = j0 + a, ii = i0 + tx;
            if (jj > ii) {
                float v = ld[tx][a];
                unsigned short h = f2bf(v);
                Mh[jj * DIM + ii] = h;
                Ml[jj * DIM + ii] = f2bf(v - bf2f(h));
            }
        }
    } else {
        // X hi/lo conversion: 32 blocks x 256 thr x 16 float4
        const int xb = bid - 136;
        const float4* x4 = (const float4*)x;
        for (int it = 0; it < 16; ++it) {
            const int gid = xb * 4096 + it * 256 + threadIdx.x;
            const float4 v = x4[gid];
            ushort4 h, l;
            h.x = f2bf(v.x); l.x = f2bf(v.x - bf2f(h.x));
            h.y = f2bf(v.y); l.y = f2bf(v.y - bf2f(h.y));
            h.z = f2bf(v.z); l.z = f2bf(v.z - bf2f(h.z));
            h.w = f2bf(v.w); l.w = f2bf(v.w - bf2f(h.w));
            ((ushort4*)Xh)[gid] = h;
            ((ushort4*)Xl)[gid] = l;
        }
    }
}

// ---------------- kernel 2: bf16-split MFMA GEMM + fused dot epilogue ----------------
// grid 256 = 16 m_blk x 4 n_blk x 4 kspl ; block 256 thr = 4 waves (2 wm x 2 wn)
// tile: 64 m x 128 n x 128 k ; wave: 32m x 64n (2 sm x 4 sn of 16x16)
__global__ __launch_bounds__(256)
void gemm_quad(const float* __restrict__ x, const float* __restrict__ W,
               const unsigned short* __restrict__ Mh, const unsigned short* __restrict__ Ml,
               const unsigned short* __restrict__ Xh, const unsigned short* __restrict__ Xl,
               float* __restrict__ partial) {
    const int bid   = blockIdx.x;
    const int kspl  = bid & 3;
    const int n_blk = (bid >> 2) & 3;
    const int m_blk = bid >> 4;
    const int row0 = m_blk * 64, n0 = n_blk * 128, k0 = kspl * 128;
    const int tid = threadIdx.x;
    const int lane = tid & 63, w = tid >> 6;
    const int wm = w >> 1, wn = w & 1;
    const int r15 = lane & 15, q = lane >> 4;

    __shared__ alignas(16) unsigned short sAh[64 * 128];
    __shared__ alignas(16) unsigned short sAl[64 * 128];
    __shared__ alignas(16) unsigned short sBh[128 * 128];
    __shared__ alignas(16) unsigned short sBl[128 * 128];
    __shared__ float ybuf[2][64];

    // stage A tiles (Xh/Xl rows row0..row0+63, k window) with XOR-swizzled chunks
    #pragma unroll
    for (int s = 0; s < 4; ++s) {
        const int cid = tid + 256 * s;          // 0..1023
        const int row = cid >> 4, c = cid & 15;
        const int goff = (row0 + row) * DIM + k0 + c * 8;
        const int loff = row * 128 + ((c ^ (row & 7)) * 8);
        *(bf16x8*)(sAh + loff) = *(const bf16x8*)(Xh + goff);
        *(bf16x8*)(sAl + loff) = *(const bf16x8*)(Xl + goff);
    }
    // stage B tiles (M rows n0..n0+127 = columns, by symmetry)
    #pragma unroll
    for (int s = 0; s < 8; ++s) {
        const int cid = tid + 256 * s;          // 0..2047
        const int row = cid >> 4, c = cid & 15;
        const int goff = (n0 + row) * DIM + k0 + c * 8;
        const int loff = row * 128 + ((c ^ (row & 7)) * 8);
        *(bf16x8*)(sBh + loff) = *(const bf16x8*)(Mh + goff);
        *(bf16x8*)(sBl + loff) = *(const bf16x8*)(Ml + goff);
    }
    __syncthreads();

    f32x4 acc[2][4];
    #pragma unroll
    for (int i = 0; i < 2; ++i)
        #pragma unroll
        for (int j = 0; j < 4; ++j) acc[i][j] = (f32x4){0.f, 0.f, 0.f, 0.f};

    #pragma unroll
    for (int ks = 0; ks < 4; ++ks) {
        const int c = ks * 4 + q;               // chunk-of-8 index along k
        bf16x8 ah[2], al[2];
        #pragma unroll
        for (int sm = 0; sm < 2; ++sm) {
            const int row = wm * 32 + sm * 16 + r15;
            const int off = row * 128 + ((c ^ (row & 7)) * 8);
            ah[sm] = *(const bf16x8*)(sAh + off);
            al[sm] = *(const bf16x8*)(sAl + off);
        }
        #pragma unroll
        for (int sn = 0; sn < 4; ++sn) {
            const int row = wn * 64 + sn * 16 + r15;
            const int off = row * 128 + ((c ^ (row & 7)) * 8);
            const bf16x8 bh = *(const bf16x8*)(sBh + off);
            const bf16x8 bl = *(const bf16x8*)(sBl + off);
            acc[0][sn] = __builtin_amdgcn_mfma_f32_16x16x32_bf16(ah[0], bh, acc[0][sn], 0, 0, 0);
            acc[1][sn] = __builtin_amdgcn_mfma_f32_16x16x32_bf16(ah[1], bh, acc[1][sn], 0, 0, 0);
            acc[0][sn] = __builtin_amdgcn_mfma_f32_16x16x32_bf16(al[0], bh, acc[0][sn], 0, 0, 0);
            acc[1][sn] = __builtin_amdgcn_mfma_f32_16x16x32_bf16(al[1], bh, acc[1][sn], 0, 0, 0);
            acc[0][sn] = __builtin_amdgcn_mfma_f32_16x16x32_bf16(ah[0], bl, acc[0][sn], 0, 0, 0);
            acc[1][sn] = __builtin_amdgcn_mfma_f32_16x16x32_bf16(ah[1], bl, acc[1][sn], 0, 0, 0);
        }
    }

    // fused epilogue: y_part[m] = sum_n (T[m][n] + (kspl==0 ? wl[n] : 0)) * x[m][n]
    float yl[2][4];
    #pragma unroll
    for (int i = 0; i < 2; ++i)
        #pragma unroll
        for (int j = 0; j < 4; ++j) yl[i][j] = 0.f;

    #pragma unroll
    for (int sn = 0; sn < 4; ++sn) {
        const int n = n0 + wn * 64 + sn * 16 + r15;
        const float wlv = (kspl == 0) ? W[n] : 0.f;
        #pragma unroll
        for (int sm = 0; sm < 2; ++sm) {
            const int mbase = row0 + wm * 32 + sm * 16 + q * 4;
            #pragma unroll
            for (int r = 0; r < 4; ++r) {
                const float xv = x[(mbase + r) * DIM + n];
                yl[sm][r] += (acc[sm][sn][r] + wlv) * xv;
            }
        }
    }
    // butterfly over the 16-lane n-groups
    #pragma unroll
    for (int off = 1; off < 16; off <<= 1) {
        #pragma unroll
        for (int sm = 0; sm < 2; ++sm)
            #pragma unroll
            for (int r = 0; r < 4; ++r)
                yl[sm][r] += __shfl_xor(yl[sm][r], off);
    }
    if (r15 == 0) {
        #pragma unroll
        for (int sm = 0; sm < 2; ++sm)
            #pragma unroll
            for (int r = 0; r < 4; ++r)
                ybuf[wn][wm * 32 + sm * 16 + q * 4 + r] = yl[sm][r];
    }
    __syncthreads();
    if (tid < 64) {
        const float p = ybuf[0][tid] + ybuf[1][tid];
        partial[(n_blk * 4 + kspl) * BATCH + row0 + tid] = p;  // deterministic slot
    }
}

// ---------------- kernel 3: finalize ----------------
__global__ void finalize(const float* __restrict__ partial, const float* __restrict__ bias,
                         float* __restrict__ out) {
    const int t = blockIdx.x * 256 + threadIdx.x;
    float z = bias[0];
    #pragma unroll
    for (int s = 0; s < 16; ++s) z += partial[s * BATCH + t];
    out[t] = 1.0f / (1.0f + expf(-z));
}

extern "C" void kernel_launch(void* const* d_in, const int* in_sizes, int n_in,
                              void* d_out, int out_size, void* d_ws, size_t ws_size,
                              hipStream_t stream) {
    const float* x = (const float*)d_in[0];   // [1024, 512]
    const float* W = (const float*)d_in[1];   // [1, 131840]
    const float* b = (const float*)d_in[2];   // [1]
    float* out = (float*)d_out;               // [1024]

    unsigned short* us = (unsigned short*)d_ws;
    unsigned short* Mh = us + MH_OFF;
    unsigned short* Ml = us + ML_OFF;
    unsigned short* Xh = us + XH_OFF;
    unsigned short* Xl = us + XL_OFF;
    float* partial = (float*)((char*)d_ws + PART_BYTE_OFF);

    hipLaunchKernelGGL(prep,      dim3(168), dim3(256), 0, stream, x, W, Mh, Ml, Xh, Xl);
    hipLaunchKernelGGL(gemm_quad, dim3(256), dim3(256), 0, stream, x, W, Mh, Ml, Xh, Xl, partial);
    hipLaunchKernelGGL(finalize,  dim3(4),   dim3(256), 0, stream, partial, b, out);
}